// Round 7
// baseline (171.217 us; speedup 1.0000x reference)
//
#include <hip/hip_runtime.h>
#include <hip/hip_bf16.h>

// CondLaneHead via bf16 MFMA 16x16x32, 3 layers fused. Round 16.
// 32 instances (4 img x 8), C=64, H=160, W=256, L=40960 px.
//
// r15 post-mortem: latency-bound AND grid-starved. Reconciling counters as
// per-CU-any-SIMD: per-wave issue ~11k cy; 7 waves/CU x 11k / 144k wall =
// 37% VALU + 13% MFMA (matches measured). Per-SIMD issue util ~12.5% ->
// waves stalled ~90%, only 1.75 waves/SIMD resident to cover. Duration has
// tracked WAVE COUNT across all rounds (5120-wave variants: 48us; 2560-wave:
// 54-62us). Issue-work floor at full hiding ~11-12us.
// r16 single change: INSTANCE-SPLIT grid dim3(160,4,2) — each block does 4
// instances (z*4..z*4+3). Waves double to 5120 with weight re-read traffic
// UNCHANGED (each instance still read by the same 640 pixel-waves; splitting
// the pixel dim instead would have doubled it). Unrolled body halves too.
// Skeleton stays r15: no LDS, no barriers, weights straight from ws via
// coalesced global loads (L2/L3-resident, 377MB chip-wide ~ 11us at L2 BW).
//
// Frag layouts (m89/m120-verified): A[m=lane&15][k=(lane>>4)*8+j],
// B[k=(lane>>4)*8+j][n=lane&15], D[row=(lane>>4)*4+r][col=lane&15].
//
// ws per instance (ISTRIDE=18432B):
//   [0,8192)       w0 A-frags, frag(mt,kst)=mt*2+kst, 1KB each (lane*16)
//   [8192,9216)    vecA f32: b0[64] wx[64] wy[64] (+pad)
//   [9216,17408)   w1 A-frags, same layout
//   [17408,18432)  vecB f32: b1[64] w2[64] b2 (+pad)

#define NP 8513
#define HW 40960
#define ISTRIDE 18432
#define OFF_VECA 8192
#define OFF_W1 9216
#define OFF_VECB 17408

typedef __attribute__((ext_vector_type(8))) short bf16x8;
typedef __attribute__((ext_vector_type(4))) float f32x4;
typedef __attribute__((ext_vector_type(2))) unsigned uint2v;

__device__ inline unsigned short f2bf(float f) {
  union { float f; unsigned u; } v; v.f = f;
  unsigned r = v.u + 0x7fffu + ((v.u >> 16) & 1u);   // RNE
  return (unsigned short)(r >> 16);
}
__device__ inline unsigned pk2(float a, float b) {   // [lo=a, hi=b] bf16x2
  __hip_bfloat162 h = __float22bfloat162_rn(float2{a, b});
  union { __hip_bfloat162 h; unsigned u; } v; v.h = h;
  return v.u;
}

__global__ void condlane_prep(const float* __restrict__ params,
                              char* __restrict__ ws) {
  const int inst = blockIdx.x >> 3, part = blockIdx.x & 7;
  const float* __restrict__ p = params + inst * NP;
  char* base = ws + inst * ISTRIDE;
  const int t = threadIdx.x;
  if (part < 4) {            // w0 A-frags (K=64), quarter each
    unsigned short* dst = (unsigned short*)base;
#pragma unroll
    for (int it = 0; it < 4; it++) {
      const int e = (part * 4 + it) * 256 + t;
      const int frag = e >> 9, lane = (e >> 3) & 63, j = e & 7;
      const int m = (frag >> 1) * 16 + (lane & 15);
      const int k = (frag & 1) * 32 + ((lane >> 4) << 3) + j;
      dst[e] = f2bf(p[m * 66 + 2 + k]);
    }
  } else {                   // w1 A-frags quarter (+ vecs on part 4)
    unsigned short* dst = (unsigned short*)(base + OFF_W1);
#pragma unroll
    for (int it = 0; it < 4; it++) {
      const int e = ((part - 4) * 4 + it) * 256 + t;
      const int frag = e >> 9, lane = (e >> 3) & 63, j = e & 7;
      const int m = (frag >> 1) * 16 + (lane & 15);
      const int k = (frag & 1) * 32 + ((lane >> 4) << 3) + j;
      dst[e] = f2bf(p[4224 + m * 64 + k]);
    }
    if (part == 4) {
      float* vA = (float*)(base + OFF_VECA);
      float* vB = (float*)(base + OFF_VECB);
      if (t < 64) {
        vA[t]       = p[8384 + t];    // b0
        vA[64 + t]  = p[t * 66];      // wx
        vA[128 + t] = p[t * 66 + 1];  // wy
        vB[t]       = p[8448 + t];    // b1
        vB[64 + t]  = p[8320 + t];    // w2
      } else if (t == 64) vB[128] = p[8512] - 2.19f;
    }
  }
}

__global__ __launch_bounds__(256, 4) void condlane_main(
    const float* __restrict__ x, const char* __restrict__ ws,
    float* __restrict__ out) {
  // NO shared memory, NO barriers: every wave is an independent program.
  const int img = blockIdx.y, row = blockIdx.x, zi = blockIdx.z;
  const int tid = threadIdx.x, lane = tid & 63, wave = tid >> 6;
  const int col = lane & 15, q = lane >> 4;
  // this block's 4 instances: img*8 + zi*4 + [0..4)
  const char* const wsb = ws + (img * 8 + zi * 4) * ISTRIDE;

  // ---- x B-frags: 64px/wave (nt=4), reused across the 4 instances ----
  bf16x8 bfr[4][2];
  {
    const float* gx = x + img * 64 * HW + row * 256 + wave * 64;
#pragma unroll
    for (int nt = 0; nt < 4; nt++)
#pragma unroll
      for (int ks = 0; ks < 2; ks++) {
        float f[8];
#pragma unroll
        for (int j = 0; j < 8; j++)
          f[j] = gx[(ks * 32 + q * 8 + j) * HW + nt * 16 + col];
        union { bf16x8 v; unsigned d[4]; } u;
#pragma unroll
        for (int jj = 0; jj < 4; jj++) u.d[jj] = pk2(f[2 * jj], f[2 * jj + 1]);
        bfr[nt][ks] = u.v;
      }
  }

  const float fyv = (float)row;
  float fxv[4];
#pragma unroll
  for (int nt = 0; nt < 4; nt++) fxv[nt] = (float)(wave * 64 + nt * 16 + col);
  float* const outb = out + (img * 8 + zi * 4) * HW + row * 256 + wave * 64;

  for (int i = 0; i < 4; i++) {
    const char* const wb = wsb + i * ISTRIDE;          // global, L2-resident
    const float* const vecA = (const float*)(wb + OFF_VECA);
    const float* const vecB = (const float*)(wb + OFF_VECB);

    // ---- layer 1: C-init = b0 + wy*fy + wx*fx (exact fp32), K=64 MFMA ----
    f32x4 acc[4][4];
#pragma unroll
    for (int mt = 0; mt < 4; mt++) {
      const int ro = mt * 16 + q * 4;
      const f32x4 b0v = *(const f32x4*)(vecA + ro);    // 64B broadcast gather
      const f32x4 wxv = *(const f32x4*)(vecA + 64 + ro);
      const f32x4 wyv = *(const f32x4*)(vecA + 128 + ro);
      const f32x4 byv = b0v + wyv * fyv;
#pragma unroll
      for (int nt = 0; nt < 4; nt++) acc[mt][nt] = byv + wxv * fxv[nt];
    }
#pragma unroll
    for (int mt = 0; mt < 4; mt++) {
      // coalesced global_load_dwordx4 (64 lanes x 16B = 1KB contiguous)
      const bf16x8 a0 = *(const bf16x8*)(wb + (mt * 2 + 0) * 1024 + lane * 16);
      const bf16x8 a1 = *(const bf16x8*)(wb + (mt * 2 + 1) * 1024 + lane * 16);
#pragma unroll
      for (int nt = 0; nt < 4; nt++) {
        f32x4 c = __builtin_amdgcn_mfma_f32_16x16x32_bf16(a0, bfr[nt][0],
                                                          acc[mt][nt], 0, 0, 0);
        acc[mt][nt] = __builtin_amdgcn_mfma_f32_16x16x32_bf16(a1, bfr[nt][1],
                                                              c, 0, 0, 0);
      }
    }

    // ---- relu -> bf16 pack -> permlane transpose, per nt ----
    bf16x8 hbf[4][2];
#pragma unroll
    for (int nt = 0; nt < 4; nt++) {
      unsigned pd[4][2];
#pragma unroll
      for (int mt = 0; mt < 4; mt++) {
        const f32x4 v = acc[mt][nt];
        pd[mt][0] = pk2(fmaxf(v.x, 0.f), fmaxf(v.y, 0.f));
        pd[mt][1] = pk2(fmaxf(v.z, 0.f), fmaxf(v.w, 0.f));
      }
#pragma unroll
      for (int ks = 0; ks < 2; ks++) {   // distinct operands (r10-proven)
        uint2v r0 = __builtin_amdgcn_permlane32_swap(
            pd[2 * ks][0], pd[2 * ks + 1][0], false, false);
        uint2v s0 = __builtin_amdgcn_permlane16_swap(r0[0], r0[1], false, false);
        uint2v r1 = __builtin_amdgcn_permlane32_swap(
            pd[2 * ks][1], pd[2 * ks + 1][1], false, false);
        uint2v s1 = __builtin_amdgcn_permlane16_swap(r1[0], r1[1], false, false);
        union { unsigned d[4]; bf16x8 v; } u;
        u.d[0] = s0[0];   // ch +0,1
        u.d[1] = s1[0];   // ch +2,3
        u.d[2] = s0[1];   // ch +4,5
        u.d[3] = s1[1];   // ch +6,7
        hbf[nt][ks] = u.v;
      }
    }

    // ---- layer 2 (C=b1) + layer 3 dot(w2, relu), 4 independent chains ----
    float s[4] = {0.f, 0.f, 0.f, 0.f};
#pragma unroll
    for (int mt = 0; mt < 4; mt++) {
      const bf16x8 a0 = *(const bf16x8*)(wb + OFF_W1 + (mt * 2 + 0) * 1024 + lane * 16);
      const bf16x8 a1 = *(const bf16x8*)(wb + OFF_W1 + (mt * 2 + 1) * 1024 + lane * 16);
      const int ro = mt * 16 + q * 4;
      const f32x4 cb  = *(const f32x4*)(vecB + ro);
      const f32x4 w2v = *(const f32x4*)(vecB + 64 + ro);
#pragma unroll
      for (int nt = 0; nt < 4; nt++) {
        f32x4 c = __builtin_amdgcn_mfma_f32_16x16x32_bf16(a0, hbf[nt][0], cb, 0, 0, 0);
        const f32x4 v = __builtin_amdgcn_mfma_f32_16x16x32_bf16(a1, hbf[nt][1], c, 0, 0, 0);
        s[nt] += w2v.x * fmaxf(v.x, 0.f) + w2v.y * fmaxf(v.y, 0.f) +
                 w2v.z * fmaxf(v.z, 0.f) + w2v.w * fmaxf(v.w, 0.f);
      }
    }
    const float b2i = vecB[128];

    // ---- q-reduction (sum lanes q=0..3 per col): proven shfl_xor ----
#pragma unroll
    for (int nt = 0; nt < 4; nt++) {
      float r = s[nt];
      r += __shfl_xor(r, 16, 64);
      r += __shfl_xor(r, 32, 64);
      if (lane < 16) outb[i * HW + nt * 16 + col] = r + b2i;
    }
  }
}

extern "C" void kernel_launch(void* const* d_in, const int* in_sizes, int n_in,
                              void* d_out, int out_size, void* d_ws, size_t ws_size,
                              hipStream_t stream) {
  const float* x      = (const float*)d_in[0];  // [4,64,160,256] fp32
  const float* params = (const float*)d_in[1];  // [32,8513] fp32
  // d_in[2] = num_ins (static 8/img; inst mapping hardcoded)
  float* out = (float*)d_out;

  condlane_prep<<<256, 256, 0, stream>>>(params, (char*)d_ws);   // 590 KB used
  condlane_main<<<dim3(160, 4, 2), 256, 0, stream>>>(x, (const char*)d_ws, out);
}

// Round 8
// 116.321 us; speedup vs baseline: 1.4719x; 1.4719x over previous
//
#include <hip/hip_runtime.h>
#include <hip/hip_bf16.h>

// CondLaneHead via bf16 MFMA 16x16x32, 3 layers fused. Round 17.
// 32 instances (4 img x 8), C=64, H=160, W=256, L=40960 px.
//
// r16 post-mortem: WRITE_SIZE 74MB / FETCH 162MB = scratch spill (r8
// signature). Cause: launch_bounds(256,4) + auto-unrolled 4-inst loop ->
// VGPR demand >> cap -> compiler spilled to the 64-VGPR tier. The z-split
// itself was never tested. r17 re-runs it clean:
//   - R13-PROVEN LDS double-buffer skeleton (never corrupted): full-instance
//     DMA into the other buffer at loop top, ONE __syncthreads()/iter.
//   - 32 px/wave nt=2 (R10's measured amortization sweet spot).
//   - grid dim3(320,4,2): z splits instances 2x4 -> half the per-block
//     serial chain (4 barrier-drains vs 8), 2x block turnover smooths the
//     dispatch tail (r10's tail: 256 blocks at 1 block/CU).
//   - #pragma unroll 1 on the instance loop (prevent r16's unroll-spill).
//   - launch_bounds(256,4): body ~ r9's 68 VGPR << 128 cap (r13 precedent).
// DMA traffic unchanged (each block stages only its own 4 instances).
//
// Frag layouts (m89/m120-verified): A[m=lane&15][k=(lane>>4)*8+j],
// B[k=(lane>>4)*8+j][n=lane&15], D[row=(lane>>4)*4+r][col=lane&15].
//
// ws per instance (ISTRIDE=18432B), identical layout in LDS:
//   [0,8192)       w0 A-frags, frag(mt,kst)=mt*2+kst, 1KB each (lane*16)
//   [8192,9216)    vecA f32: b0[64] wx[64] wy[64] (+pad, DMA'd, unread)
//   [9216,17408)   w1 A-frags, same layout
//   [17408,18432)  vecB f32: b1[64] w2[64] b2 (+pad)

#define NP 8513
#define HW 40960
#define ISTRIDE 18432
#define OFF_VECA 8192
#define OFF_W1 9216
#define OFF_VECB 17408

typedef __attribute__((ext_vector_type(8))) short bf16x8;
typedef __attribute__((ext_vector_type(4))) float f32x4;
typedef __attribute__((ext_vector_type(2))) unsigned uint2v;

__device__ inline unsigned short f2bf(float f) {
  union { float f; unsigned u; } v; v.f = f;
  unsigned r = v.u + 0x7fffu + ((v.u >> 16) & 1u);   // RNE
  return (unsigned short)(r >> 16);
}
__device__ inline unsigned pk2(float a, float b) {   // [lo=a, hi=b] bf16x2
  __hip_bfloat162 h = __float22bfloat162_rn(float2{a, b});
  union { __hip_bfloat162 h; unsigned u; } v; v.h = h;
  return v.u;
}
// async global->LDS, 16B/lane; lds dest is wave-uniform base (+lane*16 by HW)
__device__ inline void gld16(const void* g, void* l) {
  __builtin_amdgcn_global_load_lds(
      (const __attribute__((address_space(1))) unsigned*)g,
      (__attribute__((address_space(3))) unsigned*)l, 16, 0, 0);
}

__global__ void condlane_prep(const float* __restrict__ params,
                              char* __restrict__ ws) {
  const int inst = blockIdx.x >> 3, part = blockIdx.x & 7;
  const float* __restrict__ p = params + inst * NP;
  char* base = ws + inst * ISTRIDE;
  const int t = threadIdx.x;
  if (part < 4) {            // w0 A-frags (K=64), quarter each
    unsigned short* dst = (unsigned short*)base;
#pragma unroll
    for (int it = 0; it < 4; it++) {
      const int e = (part * 4 + it) * 256 + t;
      const int frag = e >> 9, lane = (e >> 3) & 63, j = e & 7;
      const int m = (frag >> 1) * 16 + (lane & 15);
      const int k = (frag & 1) * 32 + ((lane >> 4) << 3) + j;
      dst[e] = f2bf(p[m * 66 + 2 + k]);
    }
  } else {                   // w1 A-frags quarter (+ vecs on part 4)
    unsigned short* dst = (unsigned short*)(base + OFF_W1);
#pragma unroll
    for (int it = 0; it < 4; it++) {
      const int e = ((part - 4) * 4 + it) * 256 + t;
      const int frag = e >> 9, lane = (e >> 3) & 63, j = e & 7;
      const int m = (frag >> 1) * 16 + (lane & 15);
      const int k = (frag & 1) * 32 + ((lane >> 4) << 3) + j;
      dst[e] = f2bf(p[4224 + m * 64 + k]);
    }
    if (part == 4) {
      float* vA = (float*)(base + OFF_VECA);
      float* vB = (float*)(base + OFF_VECB);
      if (t < 64) {
        vA[t]       = p[8384 + t];    // b0
        vA[64 + t]  = p[t * 66];      // wx
        vA[128 + t] = p[t * 66 + 1];  // wy
        vB[t]       = p[8448 + t];    // b1
        vB[64 + t]  = p[8320 + t];    // w2
      } else if (t == 64) vB[128] = p[8512] - 2.19f;
    }
  }
}

__global__ __launch_bounds__(256, 4) void condlane_main(
    const float* __restrict__ x, const char* __restrict__ ws,
    float* __restrict__ out) {
  // [0,18432) weight buf0, [18432,36864) buf1 — r13-proven double buffer
  __shared__ __align__(16) char smem[2 * ISTRIDE];
  const int img = blockIdx.y, bx = blockIdx.x, zi = blockIdx.z;
  const int tid = threadIdx.x, lane = tid & 63, wave = tid >> 6;
  const int col = lane & 15, q = lane >> 4;
  // this block's 4 instances: img*8 + zi*4 + [0..4)
  const char* const wsb = ws + (img * 8 + zi * 4) * ISTRIDE;

  // full-instance DMA (18 x 1KB units): 4/wave + extra unit on waves 0,1
  auto dma = [&](int i, char* buf) {
    const char* src = wsb + i * ISTRIDE;
#pragma unroll
    for (int u = 0; u < 4; u++) {
      const int off = (wave * 4 + u) * 1024;
      gld16(src + off + lane * 16, buf + off);
    }
    if (wave < 2) {
      const int off = (16 + wave) * 1024;
      gld16(src + off + lane * 16, buf + off);
    }
  };
  dma(0, smem);   // inst-0 weights in flight during x loads

  // ---- x B-frags: 32px/wave (nt=2), reused across the 4 instances ----
  bf16x8 bfr[2][2];
  {
    const float* gx = x + img * 64 * HW + bx * 128 + wave * 32;
#pragma unroll
    for (int nt = 0; nt < 2; nt++)
#pragma unroll
      for (int ks = 0; ks < 2; ks++) {
        float f[8];
#pragma unroll
        for (int j = 0; j < 8; j++)
          f[j] = gx[(ks * 32 + q * 8 + j) * HW + nt * 16 + col];
        union { bf16x8 v; unsigned d[4]; } u;
#pragma unroll
        for (int jj = 0; jj < 4; jj++) u.d[jj] = pk2(f[2 * jj], f[2 * jj + 1]);
        bfr[nt][ks] = u.v;
      }
  }
  __syncthreads();   // vmcnt(0)+barrier: inst-0 DMA landed, visible to all

  const float fyv = (float)(bx >> 1);
  const float fx0 = (float)((bx & 1) * 128 + wave * 32 + col);
  float* const outb = out + (img * 8 + zi * 4) * HW + bx * 128 + wave * 32;

#pragma unroll 1
  for (int i = 0; i < 4; i++) {
    char* const wb = smem + (i & 1) * ISTRIDE;
    if (i < 3) dma(i + 1, smem + ((i + 1) & 1) * ISTRIDE);  // async fill
    const float* const vecA = (const float*)(wb + OFF_VECA);
    const float* const vecB = (const float*)(wb + OFF_VECB);

    // ---- layer 1: C-init = b0 + wy*fy + wx*fx (exact fp32), K=64 MFMA ----
    f32x4 acc[4][2];
#pragma unroll
    for (int mt = 0; mt < 4; mt++) {
      const int ro = mt * 16 + q * 4;
      const f32x4 b0v = *(const f32x4*)(vecA + ro);       // broadcast b128
      const f32x4 wxv = *(const f32x4*)(vecA + 64 + ro);
      const f32x4 wyv = *(const f32x4*)(vecA + 128 + ro);
      const f32x4 byv = b0v + wyv * fyv;
      acc[mt][0] = byv + wxv * fx0;
      acc[mt][1] = byv + wxv * (fx0 + 16.0f);
    }
#pragma unroll
    for (int mt = 0; mt < 4; mt++) {
      const bf16x8 a0 = *(const bf16x8*)(wb + (mt * 2 + 0) * 1024 + lane * 16);
      const bf16x8 a1 = *(const bf16x8*)(wb + (mt * 2 + 1) * 1024 + lane * 16);
#pragma unroll
      for (int nt = 0; nt < 2; nt++) {
        f32x4 c = __builtin_amdgcn_mfma_f32_16x16x32_bf16(a0, bfr[nt][0],
                                                          acc[mt][nt], 0, 0, 0);
        acc[mt][nt] = __builtin_amdgcn_mfma_f32_16x16x32_bf16(a1, bfr[nt][1],
                                                              c, 0, 0, 0);
      }
    }

    // ---- relu -> bf16 pack -> permlane transpose, per nt ----
    bf16x8 hbf[2][2];
#pragma unroll
    for (int nt = 0; nt < 2; nt++) {
      unsigned pd[4][2];
#pragma unroll
      for (int mt = 0; mt < 4; mt++) {
        const f32x4 v = acc[mt][nt];
        pd[mt][0] = pk2(fmaxf(v.x, 0.f), fmaxf(v.y, 0.f));
        pd[mt][1] = pk2(fmaxf(v.z, 0.f), fmaxf(v.w, 0.f));
      }
#pragma unroll
      for (int ks = 0; ks < 2; ks++) {   // distinct operands (r10-proven)
        uint2v r0 = __builtin_amdgcn_permlane32_swap(
            pd[2 * ks][0], pd[2 * ks + 1][0], false, false);
        uint2v s0 = __builtin_amdgcn_permlane16_swap(r0[0], r0[1], false, false);
        uint2v r1 = __builtin_amdgcn_permlane32_swap(
            pd[2 * ks][1], pd[2 * ks + 1][1], false, false);
        uint2v s1 = __builtin_amdgcn_permlane16_swap(r1[0], r1[1], false, false);
        union { unsigned d[4]; bf16x8 v; } u;
        u.d[0] = s0[0];   // ch +0,1
        u.d[1] = s1[0];   // ch +2,3
        u.d[2] = s0[1];   // ch +4,5
        u.d[3] = s1[1];   // ch +6,7
        hbf[nt][ks] = u.v;
      }
    }

    // ---- layer 2 (C=b1) + layer 3 dot(w2, relu) fused per mt ----
    float s0 = 0.f, s1 = 0.f;
#pragma unroll
    for (int mt = 0; mt < 4; mt++) {
      const bf16x8 a0 = *(const bf16x8*)(wb + OFF_W1 + (mt * 2 + 0) * 1024 + lane * 16);
      const bf16x8 a1 = *(const bf16x8*)(wb + OFF_W1 + (mt * 2 + 1) * 1024 + lane * 16);
      const int ro = mt * 16 + q * 4;
      const f32x4 cb  = *(const f32x4*)(vecB + ro);
      const f32x4 w2v = *(const f32x4*)(vecB + 64 + ro);
      f32x4 c0 = __builtin_amdgcn_mfma_f32_16x16x32_bf16(a0, hbf[0][0], cb, 0, 0, 0);
      const f32x4 v0 = __builtin_amdgcn_mfma_f32_16x16x32_bf16(a1, hbf[0][1], c0, 0, 0, 0);
      f32x4 c1 = __builtin_amdgcn_mfma_f32_16x16x32_bf16(a0, hbf[1][0], cb, 0, 0, 0);
      const f32x4 v1 = __builtin_amdgcn_mfma_f32_16x16x32_bf16(a1, hbf[1][1], c1, 0, 0, 0);
      s0 += w2v.x * fmaxf(v0.x, 0.f) + w2v.y * fmaxf(v0.y, 0.f) +
            w2v.z * fmaxf(v0.z, 0.f) + w2v.w * fmaxf(v0.w, 0.f);
      s1 += w2v.x * fmaxf(v1.x, 0.f) + w2v.y * fmaxf(v1.y, 0.f) +
            w2v.z * fmaxf(v1.z, 0.f) + w2v.w * fmaxf(v1.w, 0.f);
    }
    const float b2i = vecB[128];

    // ---- q-reduction (sum lanes q=0..3 per col): r9-proven shfl_xor ----
    s0 += __shfl_xor(s0, 16, 64); s0 += __shfl_xor(s0, 32, 64);
    s1 += __shfl_xor(s1, 16, 64); s1 += __shfl_xor(s1, 32, 64);
    if (lane < 32)
      outb[i * HW + q * 16 + col] = (q ? s1 : s0) + b2i;

    // ONE barrier per iter: drains dma(i+1) (vmcnt0) so the other buffer is
    // ready for iter i+1; also gates the WAR for dma(i+2).
    if (i < 3) __syncthreads();
  }
}

extern "C" void kernel_launch(void* const* d_in, const int* in_sizes, int n_in,
                              void* d_out, int out_size, void* d_ws, size_t ws_size,
                              hipStream_t stream) {
  const float* x      = (const float*)d_in[0];  // [4,64,160,256] fp32
  const float* params = (const float*)d_in[1];  // [32,8513] fp32
  // d_in[2] = num_ins (static 8/img; inst mapping hardcoded)
  float* out = (float*)d_out;

  condlane_prep<<<256, 256, 0, stream>>>(params, (char*)d_ws);   // 590 KB used
  condlane_main<<<dim3(320, 4, 2), 256, 0, stream>>>(x, (const char*)d_ws, out);
}